// Round 5
// baseline (133.940 us; speedup 1.0000x reference)
//
#include <hip/hip_runtime.h>
#include <cstdint>
#include <cstddef>

#define NN 2048
#define FF 128
#define HH 64
#define OO 16
#define TBINS 2048
#define DMAX 4.0f

// f_sums lives in a PERMUTED global layout so k_main's LDS staging is a flat
// coalesced copy: float4 element E = mblk*1024 + og*256 + j*64 + q holds
// f_sums[m][4og..4og+3] for m = mblk*256 + 4q + j  (mblk<8, og<4, j<4, q<64).

// ---------------------------------------------------------------------------
// Kernel 1: piecewise-linear table for the m-MLP + zero f_sums/out.
// g(d) = mb2 + sum_h mW2[h]*relu(mW1[h]*d + mb1[h]) is piecewise linear with
// <=64 knots. Per bin store (A,B) of the segment active at the bin CENTER:
// g(d) ~= A*d + B. Straddle error <= |w1*w2|*binwidth ~ 2e-5 in m_norm on
// ~1.3% of pairs -> ~2e-5 relative on the output. grid: 8 x 256; each thread
// also zeroes 16 floats of f_sums and 16 of out (harness poisons with 0xAA).
// ---------------------------------------------------------------------------
__global__ __launch_bounds__(256) void k_table(const float* __restrict__ mW1,
                                               const float* __restrict__ mb1,
                                               const float* __restrict__ mW2,
                                               const float* __restrict__ mb2,
                                               float2* __restrict__ tab,
                                               float4* __restrict__ f_sums_z,
                                               float4* __restrict__ out_z) {
  const int b = blockIdx.x * 256 + threadIdx.x;  // 0..2047
  const float4 z = make_float4(0.f, 0.f, 0.f, 0.f);
#pragma unroll
  for (int i = 0; i < 4; ++i) {  // 2048 thr x 4 float4 = 32768 floats each
    f_sums_z[b * 4 + i] = z;
    out_z[b * 4 + i] = z;
  }
  const float d = (b + 0.5f) * (DMAX / (float)TBINS);
  float A = 0.f;
  float B = mb2[0];
#pragma unroll 8
  for (int h = 0; h < HH; ++h) {
    const float w1 = mW1[h], b1 = mb1[h], w2 = mW2[h];
    const float t = fmaf(w1, d, b1);
    if (t > 0.f) {
      A = fmaf(w1, w2, A);
      B = fmaf(b1, w2, B);
    }
  }
  tab[b] = make_float2(A, B);
}

// ---------------------------------------------------------------------------
// Kernel 2: f_sums[n][o] = sum_f ( relu(x[n,f]*fW1[f,:]+fb1[f,:]) @ fW2[f] + fb2[f] )
// Wave = 64 nodes; feature index wave-uniform (readfirstlane) so all weight
// loads scalarize to SGPRs. Cross-wave LDS reduce with slot rotation
// (o4+(lane>>1))&3 -> ds_write_b128/ds_read_b128 at the 8-lane/window floor.
// Epilogue atomics write the PERMUTED f_sums layout (see top).
// grid: (32, 16) x 256 = 2048 waves (2/SIMD). VALU-bound (~268M FMA, ~4 us).
// ---------------------------------------------------------------------------
__global__ __launch_bounds__(256) void k_fsum(const float* __restrict__ x,
                                              const float* __restrict__ fW1,
                                              const float* __restrict__ fb1,
                                              const float* __restrict__ fW2,
                                              const float* __restrict__ fb2,
                                              float* __restrict__ f_sums) {
  __shared__ float4 red[4][64][4];
  const int t = threadIdx.x;
  const int lane = t & 63;
  const int wv = __builtin_amdgcn_readfirstlane(t >> 6);
  const int n = blockIdx.x * 64 + lane;
  const int g = blockIdx.y * 4 + wv;  // 0..63, 2 features each
  float acc[16];
#pragma unroll
  for (int o = 0; o < 16; ++o) acc[o] = 0.f;
#pragma unroll
  for (int ff = 0; ff < 2; ++ff) {
    const int f = g * 2 + ff;
    const float xv = x[n * FF + f];
    const float* __restrict__ w1p = fW1 + f * HH;
    const float* __restrict__ b1p = fb1 + f * HH;
    const float4* __restrict__ w2p = (const float4*)(fW2 + (size_t)f * HH * OO);
    const float4* __restrict__ b2p = (const float4*)(fb2 + (size_t)f * OO);
    {
      const float4 q0 = b2p[0], q1 = b2p[1], q2 = b2p[2], q3 = b2p[3];
      acc[0] += q0.x;  acc[1] += q0.y;  acc[2] += q0.z;  acc[3] += q0.w;
      acc[4] += q1.x;  acc[5] += q1.y;  acc[6] += q1.z;  acc[7] += q1.w;
      acc[8] += q2.x;  acc[9] += q2.y;  acc[10] += q2.z; acc[11] += q2.w;
      acc[12] += q3.x; acc[13] += q3.y; acc[14] += q3.z; acc[15] += q3.w;
    }
#pragma unroll 4
    for (int h = 0; h < HH; ++h) {
      const float tt = fmaxf(fmaf(xv, w1p[h], b1p[h]), 0.f);
      const float4 a0 = w2p[h * 4 + 0];
      const float4 a1 = w2p[h * 4 + 1];
      const float4 a2 = w2p[h * 4 + 2];
      const float4 a3 = w2p[h * 4 + 3];
      acc[0]  = fmaf(tt, a0.x, acc[0]);
      acc[1]  = fmaf(tt, a0.y, acc[1]);
      acc[2]  = fmaf(tt, a0.z, acc[2]);
      acc[3]  = fmaf(tt, a0.w, acc[3]);
      acc[4]  = fmaf(tt, a1.x, acc[4]);
      acc[5]  = fmaf(tt, a1.y, acc[5]);
      acc[6]  = fmaf(tt, a1.z, acc[6]);
      acc[7]  = fmaf(tt, a1.w, acc[7]);
      acc[8]  = fmaf(tt, a2.x, acc[8]);
      acc[9]  = fmaf(tt, a2.y, acc[9]);
      acc[10] = fmaf(tt, a2.z, acc[10]);
      acc[11] = fmaf(tt, a2.w, acc[11]);
      acc[12] = fmaf(tt, a3.x, acc[12]);
      acc[13] = fmaf(tt, a3.y, acc[13]);
      acc[14] = fmaf(tt, a3.z, acc[14]);
      acc[15] = fmaf(tt, a3.w, acc[15]);
    }
  }
  // rotated-slot store: floor bank utilization for b128 (8 lanes/window)
#pragma unroll
  for (int o4 = 0; o4 < 4; ++o4) {
    const int slot = (o4 + (lane >> 1)) & 3;
    red[t >> 6][lane][slot] =
        make_float4(acc[o4 * 4 + 0], acc[o4 * 4 + 1], acc[o4 * 4 + 2], acc[o4 * 4 + 3]);
  }
  __syncthreads();
  const int n_l = t >> 2;
  const int o4 = t & 3;
  const int slot = (o4 + (n_l >> 1)) & 3;  // un-rotate
  const float4 s0 = red[0][n_l][slot];
  const float4 s1 = red[1][n_l][slot];
  const float4 s2 = red[2][n_l][slot];
  const float4 s3 = red[3][n_l][slot];
  // permuted f_sums address for node n2, out-group o4 (4 consecutive floats)
  const int n2 = blockIdx.x * 64 + n_l;
  float* dst = f_sums + ((n2 >> 8) << 12) + (o4 << 10) + ((n2 & 3) << 8) +
               (((n2 & 255) >> 2) << 2);
  atomicAdd(dst + 0, s0.x + s1.x + s2.x + s3.x);
  atomicAdd(dst + 1, s0.y + s1.y + s2.y + s3.y);
  atomicAdd(dst + 2, s0.z + s1.z + s2.z + s3.z);
  atomicAdd(dst + 3, s0.w + s1.w + s2.w + s3.w);
}

// ---------------------------------------------------------------------------
// Wave64 sum via DPP (rocPRIM's gfx9 sequence) — VALU pipe, zero DS traffic.
// row_shr:1,2,4,8 then row_bcast:15, row_bcast:31. Lane 63 holds the sum.
// bound_ctrl=true: out-of-range fetches read 0 (safe for sums).
// ---------------------------------------------------------------------------
__device__ __forceinline__ float wave_red_sum(float x) {
  x += __int_as_float(__builtin_amdgcn_update_dpp(0, __float_as_int(x), 0x111, 0xf, 0xf, true));
  x += __int_as_float(__builtin_amdgcn_update_dpp(0, __float_as_int(x), 0x112, 0xf, 0xf, true));
  x += __int_as_float(__builtin_amdgcn_update_dpp(0, __float_as_int(x), 0x114, 0xf, 0xf, true));
  x += __int_as_float(__builtin_amdgcn_update_dpp(0, __float_as_int(x), 0x118, 0xf, 0xf, true));
  x += __int_as_float(__builtin_amdgcn_update_dpp(0, __float_as_int(x), 0x142, 0xf, 0xf, true));
  x += __int_as_float(__builtin_amdgcn_update_dpp(0, __float_as_int(x), 0x143, 0xf, 0xf, true));
  return x;
}

// ---------------------------------------------------------------------------
// Kernel 3: out[n][o] = sum_m ( g(dist[n,m]) / nrm[n,m] ) * f_sums[m][o]
// Block = 4 waves x 4 ROWS each (16 rows/block), m-quarter = 512 m in 2
// chunks of 256. 4 rows/wave shares the 16 GEMV ds_read_b128 per chunk
// across 4 rows -> main-loop DS = 7.4K cyc/CU (vs 11.3K at 2 rows), under
// the 5.3us HBM floor. Register double-buffer on the 8 dist/nrm float4
// loads. fsT staged via flat coalesced copy from the permuted layout.
// Epilogue: DPP wave-reduce (VALU pipe, no LDS) + 64 atomics from lane 63.
// grid: 512 blocks x 256 threads, LDS 32 KB, 2 blocks/CU, 8 waves/CU.
// Pipe budget/CU: HBM 5.3us (bound), DS 3.1us, VALU ~2.7us (hidden).
// ---------------------------------------------------------------------------
__global__ __launch_bounds__(256) void k_main(const float* __restrict__ dist,
                                              const float* __restrict__ nrm,
                                              const float2* __restrict__ gtab,
                                              const float4* __restrict__ f_sums4,
                                              float* __restrict__ out) {
  __shared__ float2 tab[TBINS];    // 16 KB
  __shared__ float4 fsT[4 * 256];  // 16 KB  [og][j][q]
  const int t = threadIdx.x;
  const int lane = t & 63;
  const int w = t >> 6;
  const int mq = blockIdx.x & 3;                  // m-quarter (512 m)
  const int r0 = (blockIdx.x >> 2) * 16 + w * 4;  // wave rows r0..r0+3
  const int mbeg = mq * 512;
#pragma unroll
  for (int i = 0; i < 8; ++i) tab[t + i * 256] = gtab[t + i * 256];
  float acc[64];  // [row][o] — all indices compile-time after unroll
#pragma unroll
  for (int i = 0; i < 64; ++i) acc[i] = 0.f;
  const float scale = (float)TBINS / DMAX;
  const float* dp = dist + (size_t)r0 * NN + mbeg + lane * 4;
  const float* np = nrm + (size_t)r0 * NN + mbeg + lane * 4;
  // preload chunk 0 (4 rows x {dist,nrm})
  float4 dA[4], nA[4];
#pragma unroll
  for (int r = 0; r < 4; ++r) {
    dA[r] = *(const float4*)(dp + (size_t)r * NN);
    nA[r] = *(const float4*)(np + (size_t)r * NN);
  }
  __syncthreads();  // tab ready
#pragma unroll
  for (int c = 0; c < 2; ++c) {
    // issue next chunk's loads first — land during mn/stage/GEMV
    float4 dB[4], nB[4];
#pragma unroll
    for (int r = 0; r < 4; ++r) { dB[r] = dA[r]; nB[r] = nA[r]; }
    if (c == 0) {
#pragma unroll
      for (int r = 0; r < 4; ++r) {
        dB[r] = *(const float4*)(dp + (size_t)r * NN + 256);
        nB[r] = *(const float4*)(np + (size_t)r * NN + 256);
      }
    }
    // m_norm for 4 rows x 4 j from current regs (tab immutable after prologue)
    float mn[4][4];
#pragma unroll
    for (int r = 0; r < 4; ++r) {
      const float da[4] = {dA[r].x, dA[r].y, dA[r].z, dA[r].w};
      const float na[4] = {nA[r].x, nA[r].y, nA[r].z, nA[r].w};
#pragma unroll
      for (int j = 0; j < 4; ++j) {
        int ia = (int)(da[j] * scale);  // d in [0,4) guaranteed
        ia = ia > TBINS - 1 ? TBINS - 1 : ia;
        const float2 ab = tab[ia];
        const float g0 = fmaf(ab.x, da[j], ab.y);
        float ra = __builtin_amdgcn_rcpf(na[j]);
        ra = fmaf(ra, fmaf(-na[j], ra, 1.0f), ra);  // Newton, ~0.5 ulp
        mn[r][j] = g0 * ra;
      }
    }
    __syncthreads();  // previous chunk's fsT reads complete
    // stage chunk: flat coalesced copy (permuted layout matches fsT exactly)
    {
      const int mblk = mq * 2 + c;
#pragma unroll
      for (int i0 = 0; i0 < 1024; i0 += 256)
        fsT[i0 + t] = f_sums4[mblk * 1024 + i0 + t];
    }
    __syncthreads();
    // GEMV: 16 b128 reads shared across 4 rows; 256 FMA
#pragma unroll
    for (int j = 0; j < 4; ++j) {
#pragma unroll
      for (int og = 0; og < 4; ++og) {
        const float4 v = fsT[og * 256 + j * 64 + lane];
#pragma unroll
        for (int r = 0; r < 4; ++r) {
          acc[r * 16 + og * 4 + 0] = fmaf(mn[r][j], v.x, acc[r * 16 + og * 4 + 0]);
          acc[r * 16 + og * 4 + 1] = fmaf(mn[r][j], v.y, acc[r * 16 + og * 4 + 1]);
          acc[r * 16 + og * 4 + 2] = fmaf(mn[r][j], v.z, acc[r * 16 + og * 4 + 2]);
          acc[r * 16 + og * 4 + 3] = fmaf(mn[r][j], v.w, acc[r * 16 + og * 4 + 3]);
        }
      }
    }
#pragma unroll
    for (int r = 0; r < 4; ++r) { dA[r] = dB[r]; nA[r] = nB[r]; }
  }
  // ---- epilogue: DPP wave-reduce (VALU pipe), lane 63 atomics ----
#pragma unroll
  for (int k = 0; k < 64; ++k) acc[k] = wave_red_sum(acc[k]);
  if (lane == 63) {
#pragma unroll
    for (int k = 0; k < 64; ++k) {
      const int r = k >> 4, o = k & 15;
      atomicAdd(out + (size_t)(r0 + r) * OO + o, acc[k]);
    }
  }
}

extern "C" void kernel_launch(void* const* d_in, const int* in_sizes, int n_in,
                              void* d_out, int out_size, void* d_ws, size_t ws_size,
                              hipStream_t stream) {
  const float* x    = (const float*)d_in[0];
  const float* dist = (const float*)d_in[1];
  const float* nrm  = (const float*)d_in[2];
  const float* fW1  = (const float*)d_in[3];
  const float* fb1  = (const float*)d_in[4];
  const float* fW2  = (const float*)d_in[5];
  const float* fb2  = (const float*)d_in[6];
  const float* mW1  = (const float*)d_in[7];
  const float* mb1  = (const float*)d_in[8];
  const float* mW2  = (const float*)d_in[9];
  const float* mb2  = (const float*)d_in[10];

  float2* tab   = (float2*)d_ws;                                   // 16 KB
  float* f_sums = (float*)((char*)d_ws + TBINS * sizeof(float2));  // 128 KB (permuted)
  float* outf   = (float*)d_out;

  // k_table also zeroes f_sums and out (harness re-poisons both with 0xAA)
  k_table<<<dim3(8), dim3(256), 0, stream>>>(mW1, mb1, mW2, mb2, tab,
                                             (float4*)f_sums, (float4*)outf);
  k_fsum<<<dim3(NN / 64, 16), dim3(256), 0, stream>>>(x, fW1, fb1, fW2, fb2, f_sums);
  k_main<<<dim3(512), dim3(256), 0, stream>>>(dist, nrm, tab, (const float4*)f_sums, outf);
}